// Round 5
// baseline (215.081 us; speedup 1.0000x reference)
//
#include <hip/hip_runtime.h>

// Fixed problem shape from setup_inputs():
//   x: [B=32, C=69, H=128, W=128] fp32, k=2, stride=2
//   out: [B=32, C=69, Ho=64, Wo=64] fp32
//   channels 0..63: 2x2 maxpool; 64..68: query-weighted stats
#define B_ 32
#define C_ 69
#define CS_ 64
#define H_ 128
#define W_ 128
#define HO_ 64
#define WO_ 64
#define HW_ (H_ * W_)
#define OHW_ (HO_ * WO_)

// Native clang vector types — __builtin_nontemporal_* requires these
// (HIP_vector_type float4/float2 are structs and are rejected).
typedef float f32x4 __attribute__((ext_vector_type(4)));
typedef float f32x2 __attribute__((ext_vector_type(2)));

// R4 = R3 with ext_vector_type fix:
//  - pooled maxes for 32 channels buffered in registers, stores issued as a
//    16 KB-per-wave burst (no fine-grained read/write interleave)
//  - nontemporal (nt) loads+stores: use-once streams skip L2 allocation
//  - per-block channel-phase stagger decorrelates the 64 KB-stride streams
__global__ __launch_bounds__(256) void spatial_pool_kernel(
        const float* __restrict__ x, float* __restrict__ out) {
    const int lane = threadIdx.x & 63;
    const int w    = threadIdx.x >> 6;       // wave 0..3
    const int p    = lane & 31;              // pixel-pair index (out cols 2p, 2p+1)
    const int rsel = lane >> 5;              // row within wave's row pair
    const int blk  = blockIdx.x;
    const int b    = blk >> 3;
    const int ho   = (blk & 7) * 8 + w * 2 + rsel;

    const float* xb = x   + (size_t)b * (C_ * HW_);
    float*       ob = out + (size_t)b * (C_ * OHW_);

    const int base0 = (2 * ho) * W_ + 4 * p;   // window row 0 (16B aligned)
    const int base1 = base0 + W_;              // window row 1
    const int opix  = ho * WO_ + 2 * p;
    const int off   = (blk * 11) & 31;         // channel-phase stagger

    // per-window-pixel |x| sums; a = pixel0 (cols 4p,4p+1), b = pixel1
    float Sa0 = 0.f, Sa1 = 0.f, Sa2 = 0.f, Sa3 = 0.f;
    float Sb0 = 0.f, Sb1 = 0.f, Sb2 = 0.f, Sb3 = 0.f;

    // --- pooled channels in 2 groups of 32: read burst, then write burst ---
    for (int g = 0; g < 2; ++g) {
        f32x2 mx[32];
        #pragma unroll
        for (int i = 0; i < 32; ++i) {
            const int c = g * 32 + ((i + off) & 31);
            const float* xc = xb + c * HW_;
            f32x4 r0 = __builtin_nontemporal_load((const f32x4*)(xc + base0));
            f32x4 r1 = __builtin_nontemporal_load((const f32x4*)(xc + base1));
            Sa0 += fabsf(r0.x); Sa1 += fabsf(r0.y);
            Sa2 += fabsf(r1.x); Sa3 += fabsf(r1.y);
            Sb0 += fabsf(r0.z); Sb1 += fabsf(r0.w);
            Sb2 += fabsf(r1.z); Sb3 += fabsf(r1.w);
            mx[i].x = fmaxf(fmaxf(r0.x, r0.y), fmaxf(r1.x, r1.y));
            mx[i].y = fmaxf(fmaxf(r0.z, r0.w), fmaxf(r1.z, r1.w));
        }
        #pragma unroll
        for (int i = 0; i < 32; ++i) {
            const int c = g * 32 + ((i + off) & 31);
            __builtin_nontemporal_store(mx[i], (f32x2*)(ob + c * OHW_ + opix));
        }
    }

    // --- tail channels 64..68: stash window values in registers ---
    f32x4 t0[5], t1[5];
    #pragma unroll
    for (int d = 0; d < 5; ++d) {
        const float* xc = xb + (CS_ + d) * HW_;
        t0[d] = __builtin_nontemporal_load((const f32x4*)(xc + base0));
        t1[d] = __builtin_nontemporal_load((const f32x4*)(xc + base1));
        Sa0 += fabsf(t0[d].x); Sa1 += fabsf(t0[d].y);
        Sa2 += fabsf(t1[d].x); Sa3 += fabsf(t1[d].y);
        Sb0 += fabsf(t0[d].z); Sb1 += fabsf(t0[d].w);
        Sb2 += fabsf(t1[d].z); Sb3 += fabsf(t1[d].w);
    }

    // ---- stats for both pixels (1/sqrt(cs) scale cancels in q) ----
    f32x2 res[5];
    #pragma unroll
    for (int pix = 0; pix < 2; ++pix) {
        float q0, q1, q2, q3;
        float v64[4], v65[4], v66[4], v67[4], v68[4];
        if (pix == 0) {
            q0 = Sa0; q1 = Sa1; q2 = Sa2; q3 = Sa3;
            v64[0] = t0[0].x; v64[1] = t0[0].y; v64[2] = t1[0].x; v64[3] = t1[0].y;
            v65[0] = t0[1].x; v65[1] = t0[1].y; v65[2] = t1[1].x; v65[3] = t1[1].y;
            v66[0] = t0[2].x; v66[1] = t0[2].y; v66[2] = t1[2].x; v66[3] = t1[2].y;
            v67[0] = t0[3].x; v67[1] = t0[3].y; v67[2] = t1[3].x; v67[3] = t1[3].y;
            v68[0] = t0[4].x; v68[1] = t0[4].y; v68[2] = t1[4].x; v68[3] = t1[4].y;
        } else {
            q0 = Sb0; q1 = Sb1; q2 = Sb2; q3 = Sb3;
            v64[0] = t0[0].z; v64[1] = t0[0].w; v64[2] = t1[0].z; v64[3] = t1[0].w;
            v65[0] = t0[1].z; v65[1] = t0[1].w; v65[2] = t1[1].z; v65[3] = t1[1].w;
            v66[0] = t0[2].z; v66[1] = t0[2].w; v66[2] = t1[2].z; v66[3] = t1[2].w;
            v67[0] = t0[3].z; v67[1] = t0[3].w; v67[2] = t1[3].z; v67[3] = t1[3].w;
            v68[0] = t0[4].z; v68[1] = t0[4].w; v68[2] = t1[4].z; v68[3] = t1[4].w;
        }
        float inv = 1.0f / (q0 + q1 + q2 + q3);
        float q[4] = {q0 * inv, q1 * inv, q2 * inv, q3 * inv};

        float m0 = 0.f, m1 = 0.f;
        #pragma unroll
        for (int j = 0; j < 4; ++j) {
            m0 += v64[j] * q[j];
            m1 += v65[j] * q[j];
        }
        float vv0 = 0.f, vv1 = 0.f, cv = 0.f;
        #pragma unroll
        for (int j = 0; j < 4; ++j) {
            float d0 = v64[j] - m0;
            float d1 = v65[j] - m1;
            vv0 += v66[j] * q[j] + d0 * d0 * q[j];
            vv1 += v67[j] * q[j] + d1 * d1 * q[j];
            cv  += v68[j] * q[j] + d0 * d1 * q[j] * q[j];
        }
        if (pix == 0) {
            res[0].x = m0; res[1].x = m1; res[2].x = vv0; res[3].x = vv1; res[4].x = cv;
        } else {
            res[0].y = m0; res[1].y = m1; res[2].y = vv0; res[3].y = vv1; res[4].y = cv;
        }
    }

    #pragma unroll
    for (int d = 0; d < 5; ++d)
        __builtin_nontemporal_store(res[d], (f32x2*)(ob + (CS_ + d) * OHW_ + opix));
}

extern "C" void kernel_launch(void* const* d_in, const int* in_sizes, int n_in,
                              void* d_out, int out_size, void* d_ws, size_t ws_size,
                              hipStream_t stream) {
    const float* x = (const float*)d_in[0];
    float* out = (float*)d_out;
    const int grid = B_ * (HO_ / 8);   // 256 blocks, 256 threads, 2 pixels/thread
    spatial_pool_kernel<<<grid, 256, 0, stream>>>(x, out);
}